// Round 7
// baseline (215.554 us; speedup 1.0000x reference)
//
#include <hip/hip_runtime.h>
#include <math.h>

// Problem constants
static constexpr int Bn   = 32;
static constexpr int Tn   = 512;
static constexpr int Cn   = 128;
static constexpr int Kk   = 3;
static constexpr int NLAG = 57;   // lags 8..64 inclusive
static constexpr int CYC  = 64;   // CYC_MAX
static constexpr int KWn  = 9;

// ---------------------------------------------------------------------------
// K1: heterogeneous front kernel.
//   blocks [0,1024): autocorr partials (b, lag-group of 8, t-quarter)
//   blocks [1024,1056): per-(b,c) prefix sums P[t] = sum_{s<t} x[b,s,c]
// ---------------------------------------------------------------------------
__global__ __launch_bounds__(256, 3) void k_front(const float* __restrict__ x,
    float* __restrict__ r_ws, float* __restrict__ Pp) {
  const int bk  = blockIdx.x;
  const int tid = threadIdx.x;
  __shared__ float lds_r[4][8];
  __shared__ float csum[8][128];
  __shared__ float coff[8][128];

  if (bk < 1024) {
    const int b   = bk >> 5;
    const int grp = (bk >> 2) & 7;
    const int th  = bk & 3;
    const int L0  = 8 + grp * 8;
    const float4* X4 = (const float4*)(x + (size_t)b * Tn * Cn);  // [512][32]

    float acc[8];
#pragma unroll
    for (int i = 0; i < 8; ++i) acc[i] = 0.f;

#pragma unroll
    for (int s = 0; s < 2; ++s) {
      const int id = (th * 2 + s) * 256 + tid;
      const int c4 = id & 31;
      const int t0 = (id >> 5) * 8;
      float4 A[8];
#pragma unroll
      for (int j = 0; j < 8; ++j) A[j] = X4[(t0 + j) * 32 + c4];
      float4 R[16];
#pragma unroll
      for (int j = 0; j < 16; ++j) R[j] = X4[((t0 + L0 + j) & 511) * 32 + c4];
#pragma unroll
      for (int g = 0; g < 8; ++g) {
#pragma unroll
        for (int j = 0; j < 8; ++j) {
          const float4 a = A[j];
          const float4 r = R[g + j];
          acc[g] += a.x * r.x + a.y * r.y + a.z * r.z + a.w * r.w;
        }
      }
    }

    const int lane = tid & 63, wave = tid >> 6;
#pragma unroll
    for (int g = 0; g < 8; ++g) {
      float v = acc[g];
#pragma unroll
      for (int m = 32; m > 0; m >>= 1) v += __shfl_xor(v, m, 64);
      if (lane == 0) lds_r[wave][g] = v;
    }
    __syncthreads();
    if (tid < 8) {
      const int li = grp * 8 + tid;
      if (li < NLAG) {
        r_ws[(size_t)(b * 4 + th) * NLAG + li] =
            (lds_r[0][tid] + lds_r[1][tid] + lds_r[2][tid] + lds_r[3][tid]) * (1.0f / Cn);
      }
    }
  } else {
    const int b = bk - 1024;
    const float* xb = x + (size_t)b * Tn * Cn;
    float* Pb = Pp + (size_t)b * 513 * Cn;
    const int c = tid & 127, h = tid >> 7;

    for (int q = h * 4; q < h * 4 + 4; ++q) {
      float s = 0.f;
      const float* col = xb + q * 64 * Cn + c;
#pragma unroll
      for (int t = 0; t < 64; ++t) s += col[t * Cn];
      csum[q][c] = s;
    }
    __syncthreads();
    if (tid < 128) {
      float run = 0.f;
#pragma unroll
      for (int q = 0; q < 8; ++q) { coff[q][tid] = run; run += csum[q][tid]; }
      Pb[tid] = 0.f;
    }
    __syncthreads();
    for (int q = h * 4; q < h * 4 + 4; ++q) {
      float run = coff[q][c];
      const float* col = xb + q * 64 * Cn + c;
      float* pcol = Pb + (q * 64 + 1) * Cn + c;
#pragma unroll
      for (int t = 0; t < 64; ++t) { run += col[t * Cn]; pcol[t * Cn] = run; }
    }
  }
}

// ---------------------------------------------------------------------------
// K2: params. 32 blocks x 64 thr. Top-3 scan ONCE per b (was: every thread of
// every downstream block -> ~60us of serial scalar loads). Also precomputes
// cyc index tables (t/p as ushort4) for k_final.
// ---------------------------------------------------------------------------
__global__ __launch_bounds__(64) void k_params(const float* __restrict__ r_ws,
    int* __restrict__ pint, float* __restrict__ pflt, ushort4* __restrict__ cycs_g) {
  const int b = blockIdx.x;
  const int tid = threadIdx.x;

  // uniform scan (all 64 threads redundantly; registers only)
  const float* r0 = r_ws + (size_t)(b * 4 + 0) * NLAG;
  const float* r1 = r_ws + (size_t)(b * 4 + 1) * NLAG;
  const float* r2 = r_ws + (size_t)(b * 4 + 2) * NLAG;
  const float* r3 = r_ws + (size_t)(b * 4 + 3) * NLAG;
  float v0 = -INFINITY, v1 = -INFINITY, v2 = -INFINITY;
  int i0 = 0, i1 = 0, i2 = 0;
  for (int i = 0; i < NLAG; ++i) {
    const float v = r0[i] + r1[i] + r2[i] + r3[i];
    if (v > v0)      { v2 = v1; i2 = i1; v1 = v0; i1 = i0; v0 = v; i0 = i; }
    else if (v > v1) { v2 = v1; i2 = i1; v1 = v; i1 = i; }
    else if (v > v2) { v2 = v; i2 = i; }
  }
  const int p0 = i0 + 8, p1 = i1 + 8, p2 = i2 + 8;
  const float e1 = expf(v1 - v0), e2 = expf(v2 - v0);
  const float s = 1.0f + e1 + e2;
  const float w0 = 1.0f / s, w1 = e1 / s, w2 = e2 / s;
  const float H  = -(w0 * logf(w0 + 1e-8f) + w1 * logf(w1 + 1e-8f) + w2 * logf(w2 + 1e-8f));
  const float lg = logf(3.0f + 1e-8f) + 1e-8f;
  const float Gv = fminf(fmaxf(1.0f - H / lg, 0.0f), 1.0f);

  if (tid == 0) {
    pint[b * 4 + 0] = p0; pint[b * 4 + 1] = p1; pint[b * 4 + 2] = p2; pint[b * 4 + 3] = 0;
    pflt[b * 4 + 0] = w0; pflt[b * 4 + 1] = w1; pflt[b * 4 + 2] = w2; pflt[b * 4 + 3] = Gv;
  }
  ushort4* cyb = cycs_g + (size_t)b * Tn;
  for (int t = tid; t < Tn; t += 64) {
    ushort4 cy;
    cy.x = (unsigned short)(t / p0);
    cy.y = (unsigned short)(t / p1);
    cy.z = (unsigned short)(t / p2);
    cy.w = 0;
    cyb[t] = cy;
  }
}

// ---------------------------------------------------------------------------
// K3: fold (O(1) prefix) + dwconv + pointwise + GN + gelu + gate.
// grid (n=96, og=8) = 768 blocks (3/CU, 12 waves/CU), 256 thr.
// All weights staged in LDS -> inner loops are pure LDS (no s_load stalls).
// Block computes 16 outputs = 4 GN groups (one per wave).
// ---------------------------------------------------------------------------
__global__ __launch_bounds__(256) void k_foldconv(
    const float* __restrict__ Pp, const int* __restrict__ pint,
    const float* __restrict__ Wdw, const float* __restrict__ Wpw,
    const float* __restrict__ gnw, const float* __restrict__ gnb,
    const float* __restrict__ Wgate, float* __restrict__ hh) {
  const int n  = blockIdx.x;
  const int og = blockIdx.y;           // 0..7 -> outputs og*16 .. +16
  const int b  = n / 3;
  const int kk = n - b * 3;
  const int tid = threadIdx.x;
  const int l  = tid & 63;
  const int w  = tid >> 6;             // wave 0..3

  const int p = pint[b * 4 + kk];
  const int ncyc = (Tn + p - 1) / p;
  const int tpad = ncyc * p;           // in [512, 575]

  __shared__ float u_s[8320];          // u-view [64][129]; h1-view [128][65]
  __shared__ float wdw_s[Cn * KWn];    // 4.5 KB
  __shared__ float wpw_s[16 * Cn];     // 8 KB: this block's 16 Wpw rows
  __shared__ float ubar_s[Cn];
  __shared__ float gpart[16][17];
  __shared__ float gates_s[16];

  // stage weights (coalesced)
  for (int idx = tid; idx < Cn * KWn; idx += 256) wdw_s[idx] = Wdw[idx];
  {
    const float* wrow = Wpw + (size_t)og * 16 * Cn;
    for (int idx = tid; idx < 16 * Cn; idx += 256) wpw_s[idx] = wrow[idx];
  }

  const float* Pb = Pp + (size_t)b * 513 * Cn;

  // ubar closed form: sum over t in [0,tpad) of x[refl(t)] = P[512] + P[511] - P[1023-tpad]
  if (tid < Cn) {
    const float v = Pb[512 * Cn + tid] + Pb[511 * Cn + tid] - Pb[(1023 - tpad) * Cn + tid];
    ubar_s[tid] = v * (1.0f / 4096.0f);   // /64 (fold) /64 (mean over L)
  }

  // fold via prefix sums
  {
    const int c = tid & 127, h = tid >> 7;
#pragma unroll
    for (int i = 0; i < 32; ++i) {
      const int ll = h * 32 + i;
      float s = 0.f;
      if (ll < ncyc) {
        const int a = ll * p, e = a + p;      // a < 512 always
        const float pa = Pb[a * Cn + c];
        s = (e <= Tn) ? Pb[e * Cn + c] - pa
                      : Pb[Tn * Cn + c] - pa + Pb[511 * Cn + c] - Pb[(1023 - e) * Cn + c];
      }
      u_s[ll * 129 + c] = s * (1.0f / 64.0f);
    }
  }
  __syncthreads();

  // gate partials: thread (o=tid>>4, seg=tid&15), 8 c's each
  {
    const int o = og * 16 + (tid >> 4);
    const int cc = (tid & 15) * 8;
    float z = 0.f;
#pragma unroll
    for (int j = 0; j < 8; ++j) z += Wgate[o * Cn + cc + j] * ubar_s[cc + j];
    gpart[tid >> 4][tid & 15] = z;
  }

  // depthwise conv -> registers: wave w covers c = w*32..+32, lane = l
  float hreg[32];
  const int c0 = w * 32;
#pragma unroll
  for (int i = 0; i < 32; ++i) {
    const int c = c0 + i;
    float s = 0.f;
#pragma unroll
    for (int k2 = 0; k2 < KWn; ++k2) {
      const int ll = l + k2 - KWn / 2;
      if (ll >= 0 && ll < CYC) s += u_s[ll * 129 + c] * wdw_s[c * KWn + k2];
    }
    hreg[i] = s;
  }
  __syncthreads();   // u-view reads done; gpart complete

  if (tid < 16) {
    float z = 0.f;
#pragma unroll
    for (int j = 0; j < 16; ++j) z += gpart[tid][j];
    gates_s[tid] = 1.0f / (1.0f + expf(-z));
  }

  // h1-view store [c][65]
#pragma unroll
  for (int i = 0; i < 32; ++i) u_s[(c0 + i) * 65 + l] = hreg[i];
  __syncthreads();

  // pointwise: wave w -> 4 outputs; weights from LDS (uniform broadcast reads)
  const int ow = w * 4;
  float acc[4] = {0.f, 0.f, 0.f, 0.f};
  for (int c = 0; c < Cn; c += 4) {
#pragma unroll
    for (int cc = 0; cc < 4; ++cc) {
      const float hv = u_s[(c + cc) * 65 + l];
#pragma unroll
      for (int i = 0; i < 4; ++i)
        acc[i] = fmaf(wpw_s[(ow + i) * Cn + c + cc], hv, acc[i]);
    }
  }

  // GroupNorm: wave's 4 o == one GN group (4 ch x 64 l)
  float s1 = acc[0] + acc[1] + acc[2] + acc[3];
  float s2 = acc[0]*acc[0] + acc[1]*acc[1] + acc[2]*acc[2] + acc[3]*acc[3];
#pragma unroll
  for (int m = 32; m > 0; m >>= 1) {
    s1 += __shfl_xor(s1, m, 64);
    s2 += __shfl_xor(s2, m, 64);
  }
  const float mean = s1 * (1.0f / 256.0f);
  const float var  = s2 * (1.0f / 256.0f) - mean * mean;
  const float rstd = rsqrtf(var + 1e-5f);

  const int o4 = og * 16 + w * 4;
  float4 res;
  float* rp = (float*)&res;
#pragma unroll
  for (int i = 0; i < 4; ++i) {
    const int o = o4 + i;
    float h = (acc[i] - mean) * rstd;
    h = h * gnw[o] + gnb[o];
    h = 0.5f * h * (1.0f + erff(h * 0.70710678118654752440f));
    rp[i] = h * gates_s[w * 4 + i];
  }
  *(float4*)(hh + ((size_t)n * CYC + l) * Cn + o4) = res;
}

// ---------------------------------------------------------------------------
// K4: fused dot + out. grid (q=8, b=32), 512 threads (8 waves/CU).
// Full num/den computed cooperatively (th splits t), then write own chunk.
// ---------------------------------------------------------------------------
__global__ __launch_bounds__(512) void k_final(const float* __restrict__ x,
    const float* __restrict__ hh, const float* __restrict__ pflt,
    const ushort4* __restrict__ cycs_g, const float* __restrict__ gamma,
    float* __restrict__ out) {
  const int q = blockIdx.x, b = blockIdx.y;
  const int tid = threadIdx.x;
  const int c = tid & 127, th = tid >> 7;   // th 0..3
  __shared__ float redn[4][Cn], redd[4][Cn];

  const float w0 = pflt[b * 4 + 0], w1 = pflt[b * 4 + 1], w2 = pflt[b * 4 + 2];
  const float Gv = pflt[b * 4 + 3];
  const float sw = w0 + w1 + w2;

  const float gam = gamma[c];
  const float* hh0 = hh + ((size_t)(b * 3 + 0) * CYC) * Cn + c;
  const float* hh1 = hh + ((size_t)(b * 3 + 1) * CYC) * Cn + c;
  const float* hh2 = hh + ((size_t)(b * 3 + 2) * CYC) * Cn + c;
  const float* xb = x + (size_t)b * Tn * Cn;
  const ushort4* cyb = cycs_g + (size_t)b * Tn;

  float na = 0.f, da = 0.f;
  for (int tt = th * 128; tt < th * 128 + 128; ++tt) {
    const ushort4 cy = cyb[tt];
    const float xv = xb[tt * Cn + c];
    const float dv = gam * (w0 * hh0[cy.x * Cn] + w1 * hh1[cy.y * Cn] + w2 * hh2[cy.z * Cn]);
    const float P = sw * xv + dv;
    na += (xv - P) * P;
    da += P * P;
  }
  redn[th][c] = na; redd[th][c] = da;
  __syncthreads();

  const float num = redn[0][c] + redn[1][c] + redn[2][c] + redn[3][c];
  const float den = redd[0][c] + redd[1][c] + redd[2][c] + redd[3][c] + 1e-6f;
  const float sc = Gv * (num / den);

  float* ob = out + (size_t)b * Tn * Cn;
  const int t0 = q * 64 + th * 16;
  for (int tt = t0; tt < t0 + 16; ++tt) {
    const ushort4 cy = cyb[tt];
    const float xv = xb[tt * Cn + c];
    const float dv = gam * (w0 * hh0[cy.x * Cn] + w1 * hh1[cy.y * Cn] + w2 * hh2[cy.z * Cn]);
    const float P = sw * xv + dv;
    ob[tt * Cn + c] = xv - sc * P;
  }
}

// ---------------------------------------------------------------------------
extern "C" void kernel_launch(void* const* d_in, const int* in_sizes, int n_in,
                              void* d_out, int out_size, void* d_ws, size_t ws_size,
                              hipStream_t stream) {
  const float* x     = (const float*)d_in[0];
  const float* Wdw   = (const float*)d_in[1];
  const float* Wpw   = (const float*)d_in[2];
  const float* gnw   = (const float*)d_in[3];
  const float* gnb   = (const float*)d_in[4];
  const float* Wgate = (const float*)d_in[5];
  const float* gamma = (const float*)d_in[6];
  float* out = (float*)d_out;

  char* ws = (char*)d_ws;
  float*   r_ws   = (float*)ws;                   // 32*4*57 f (~29 KB)
  int*     pint   = (int*)(ws + 32768);           // 32*4 ints
  float*   pflt   = (float*)(ws + 36864);         // 32*4 f
  ushort4* cycs_g = (ushort4*)(ws + 40960);       // 32*512*8 B (128 KB)
  float*   Pp     = (float*)(ws + 262144);        // 32*513*128 f (8.4 MB)
  float*   hh     = (float*)(ws + 262144 + 8404992);  // 3 MB

  k_front<<<1024 + Bn, 256, 0, stream>>>(x, r_ws, Pp);
  k_params<<<Bn, 64, 0, stream>>>(r_ws, pint, pflt, cycs_g);
  k_foldconv<<<dim3(Bn * Kk, 8), 256, 0, stream>>>(Pp, pint, Wdw, Wpw, gnw, gnb, Wgate, hh);
  k_final<<<dim3(8, Bn), 512, 0, stream>>>(x, hh, pflt, cycs_g, gamma, out);
}

// Round 8
// 172.723 us; speedup vs baseline: 1.2480x; 1.2480x over previous
//
#include <hip/hip_runtime.h>
#include <math.h>

// Problem constants
static constexpr int Bn   = 32;
static constexpr int Tn   = 512;
static constexpr int Cn   = 128;
static constexpr int Kk   = 3;
static constexpr int NLAG = 57;   // lags 8..64 inclusive
static constexpr int CYC  = 64;   // CYC_MAX
static constexpr int KWn  = 9;

__device__ __forceinline__ float dot4(float4 a, float4 b) {
  return a.x * b.x + a.y * b.y + a.z * b.z + a.w * b.w;
}
__device__ __forceinline__ void fma4(float4& d, float4 a, float4 b) {
  d.x = fmaf(a.x, b.x, d.x); d.y = fmaf(a.y, b.y, d.y);
  d.z = fmaf(a.z, b.z, d.z); d.w = fmaf(a.w, b.w, d.w);
}

// ---------------------------------------------------------------------------
// K1: heterogeneous front.
//  blocks [0,512): autocorr, LDS-tiled: (b, t-slice of 64, c-half of 64).
//    Stage 128 rows x 16 float4 (34.8KB, stride 17 f4 -> spread banks), then
//    sweep all 57 lags from LDS with a 4-row ring window (2 passes, acc<=29).
//  blocks [512,544): per-(b,c) prefix sums P[t] = sum_{s<t} x[b,s,c]
// ---------------------------------------------------------------------------
__global__ __launch_bounds__(256, 4) void k_front(const float* __restrict__ x,
    float* __restrict__ r_ws, float* __restrict__ Pp) {
  const int bk  = blockIdx.x;
  const int tid = threadIdx.x;
  __shared__ float4 smem4[2240];          // 35.8 KB, aliased below

  if (bk < 512) {
    const int b  = bk >> 4;
    const int ts = (bk >> 1) & 7;         // t-slice: rows ts*64 .. ts*64+127
    const int ch = bk & 1;                // c-half: float4 cols ch*16 .. +16
    float4* xs4 = smem4;                  // [128][17] (pad -> even banks)
    float* lds_r = (float*)(smem4 + 2176);  // [4][57]

    const float4* X4 = (const float4*)(x + (size_t)b * Tn * Cn);  // [512][32]
    // stage
    for (int it = 0; it < 8; ++it) {
      const int idx = it * 256 + tid;
      const int row = idx >> 4, cc = idx & 15;
      xs4[row * 17 + cc] = X4[((ts * 64 + row) & 511) * 32 + ch * 16 + cc];
    }
    __syncthreads();

    const int tb = tid >> 4;              // t-block of 4 (0..15)
    const int cc = tid & 15;
    const int lane = tid & 63, wave = tid >> 6;
    float4 A[4];
#pragma unroll
    for (int j = 0; j < 4; ++j) A[j] = xs4[(tb * 4 + j) * 17 + cc];

    // ---- pass 1: lags 8..35 ----
    {
      float acc[28];
#pragma unroll
      for (int i = 0; i < 28; ++i) acc[i] = 0.f;
      float4 W[4];
#pragma unroll
      for (int j = 0; j < 4; ++j) W[j] = xs4[(tb * 4 + 8 + j) * 17 + cc];
#pragma unroll
      for (int L = 8; L <= 35; ++L) {
        const int li = L - 8;
#pragma unroll
        for (int j = 0; j < 4; ++j) acc[li] += dot4(A[j], W[(L + j) & 3]);
        if (L < 35) W[L & 3] = xs4[(tb * 4 + L + 4) * 17 + cc];
      }
#pragma unroll
      for (int i = 0; i < 28; ++i) {
        float v = acc[i];
#pragma unroll
        for (int m = 32; m > 0; m >>= 1) v += __shfl_xor(v, m, 64);
        if (lane == 0) lds_r[wave * 57 + i] = v;
      }
    }
    // ---- pass 2: lags 36..64 ----
    {
      float acc[29];
#pragma unroll
      for (int i = 0; i < 29; ++i) acc[i] = 0.f;
      float4 W[4];
#pragma unroll
      for (int j = 0; j < 4; ++j) W[j] = xs4[(tb * 4 + 36 + j) * 17 + cc];
#pragma unroll
      for (int L = 36; L <= 64; ++L) {
        const int li = L - 36;
#pragma unroll
        for (int j = 0; j < 4; ++j) acc[li] += dot4(A[j], W[(L + j) & 3]);
        if (L < 64) W[L & 3] = xs4[(tb * 4 + L + 4) * 17 + cc];
      }
#pragma unroll
      for (int i = 0; i < 29; ++i) {
        float v = acc[i];
#pragma unroll
        for (int m = 32; m > 0; m >>= 1) v += __shfl_xor(v, m, 64);
        if (lane == 0) lds_r[wave * 57 + 28 + i] = v;
      }
    }
    __syncthreads();
    if (tid < NLAG) {
      const int s = ts * 2 + ch;
      r_ws[(size_t)(b * 16 + s) * NLAG + tid] =
          (lds_r[0 * 57 + tid] + lds_r[1 * 57 + tid] +
           lds_r[2 * 57 + tid] + lds_r[3 * 57 + tid]) * (1.0f / Cn);
    }
  } else {
    // ---- prefix sums ----
    const int b = bk - 512;
    float* csum = (float*)smem4;          // [8][128]
    float* coff = (float*)smem4 + 1024;   // [8][128]
    const float* xb = x + (size_t)b * Tn * Cn;
    float* Pb = Pp + (size_t)b * 513 * Cn;
    const int c = tid & 127, h = tid >> 7;

    for (int q = h * 4; q < h * 4 + 4; ++q) {
      float s = 0.f;
      const float* col = xb + q * 64 * Cn + c;
#pragma unroll
      for (int t = 0; t < 64; ++t) s += col[t * Cn];
      csum[q * 128 + c] = s;
    }
    __syncthreads();
    if (tid < 128) {
      float run = 0.f;
#pragma unroll
      for (int q = 0; q < 8; ++q) { coff[q * 128 + tid] = run; run += csum[q * 128 + tid]; }
      Pb[tid] = 0.f;
    }
    __syncthreads();
    for (int q = h * 4; q < h * 4 + 4; ++q) {
      float run = coff[q * 128 + c];
      const float* col = xb + q * 64 * Cn + c;
      float* pcol = Pb + (q * 64 + 1) * Cn + c;
#pragma unroll
      for (int t = 0; t < 64; ++t) { run += col[t * Cn]; pcol[t * Cn] = run; }
    }
  }
}

// ---------------------------------------------------------------------------
// K2: params. Top-3 scan once per b (sums 16 partials) + cyc index tables.
// ---------------------------------------------------------------------------
__global__ __launch_bounds__(64) void k_params(const float* __restrict__ r_ws,
    int* __restrict__ pint, float* __restrict__ pflt, ushort4* __restrict__ cycs_g) {
  const int b = blockIdx.x;
  const int tid = threadIdx.x;

  float v0 = -INFINITY, v1 = -INFINITY, v2 = -INFINITY;
  int i0 = 0, i1 = 0, i2 = 0;
  const float* rb = r_ws + (size_t)b * 16 * NLAG;
  for (int i = 0; i < NLAG; ++i) {
    float v = 0.f;
#pragma unroll
    for (int s = 0; s < 16; ++s) v += rb[s * NLAG + i];
    if (v > v0)      { v2 = v1; i2 = i1; v1 = v0; i1 = i0; v0 = v; i0 = i; }
    else if (v > v1) { v2 = v1; i2 = i1; v1 = v; i1 = i; }
    else if (v > v2) { v2 = v; i2 = i; }
  }
  const int p0 = i0 + 8, p1 = i1 + 8, p2 = i2 + 8;
  const float e1 = expf(v1 - v0), e2 = expf(v2 - v0);
  const float s = 1.0f + e1 + e2;
  const float w0 = 1.0f / s, w1 = e1 / s, w2 = e2 / s;
  const float H  = -(w0 * logf(w0 + 1e-8f) + w1 * logf(w1 + 1e-8f) + w2 * logf(w2 + 1e-8f));
  const float lg = logf(3.0f + 1e-8f) + 1e-8f;
  const float Gv = fminf(fmaxf(1.0f - H / lg, 0.0f), 1.0f);

  if (tid == 0) {
    pint[b * 4 + 0] = p0; pint[b * 4 + 1] = p1; pint[b * 4 + 2] = p2; pint[b * 4 + 3] = 0;
    pflt[b * 4 + 0] = w0; pflt[b * 4 + 1] = w1; pflt[b * 4 + 2] = w2; pflt[b * 4 + 3] = Gv;
  }
  ushort4* cyb = cycs_g + (size_t)b * Tn;
  for (int t = tid; t < Tn; t += 64) {
    ushort4 cy;
    cy.x = (unsigned short)(t / p0);
    cy.y = (unsigned short)(t / p1);
    cy.z = (unsigned short)(t / p2);
    cy.w = 0;
    cyb[t] = cy;
  }
}

// ---------------------------------------------------------------------------
// K3 v5: fold (O(1) prefix) + dwconv (float4 ring) + pointwise (s_load
// weights, b128 LDS) + GN + gelu + gate. grid (n=96, og=8), 256 thr.
// ---------------------------------------------------------------------------
__global__ __launch_bounds__(256, 3) void k_foldconv(
    const float* __restrict__ Pp, const int* __restrict__ pint,
    const float* __restrict__ Wdw, const float* __restrict__ Wpw,
    const float* __restrict__ gnw, const float* __restrict__ gnb,
    const float* __restrict__ Wgate, float* __restrict__ hh) {
  const int n  = blockIdx.x;
  const int og = blockIdx.y;           // outputs og*16 .. +16
  const int b  = n / 3;
  const int kk = n - b * 3;
  const int tid = threadIdx.x;
  const int l  = tid & 63;
  const int w  = tid >> 6;             // wave 0..3

  const int p = pint[b * 4 + kk];
  const int ncyc = (Tn + p - 1) / p;
  const int tpad = ncyc * p;           // [512, 575]

  __shared__ float u_s[64 * 129];      // u-view [ll][c]; later h1-view [l][c]
  __shared__ float wdw_s[Cn * KWn];
  __shared__ float ubar_s[Cn];
  __shared__ float gpart[16][17];
  __shared__ float gates_s[16];

  for (int idx = tid; idx < Cn * KWn; idx += 256) wdw_s[idx] = Wdw[idx];

  const float* Pb = Pp + (size_t)b * 513 * Cn;
  if (tid < Cn) {
    const float v = Pb[512 * Cn + tid] + Pb[511 * Cn + tid] - Pb[(1023 - tpad) * Cn + tid];
    ubar_s[tid] = v * (1.0f / 4096.0f);
  }

  // fold via prefix sums
  {
    const int c = tid & 127, h = tid >> 7;
#pragma unroll
    for (int i = 0; i < 32; ++i) {
      const int ll = h * 32 + i;
      float s = 0.f;
      if (ll < ncyc) {
        const int a = ll * p, e = a + p;
        const float pa = Pb[a * Cn + c];
        s = (e <= Tn) ? Pb[e * Cn + c] - pa
                      : Pb[Tn * Cn + c] - pa + Pb[511 * Cn + c] - Pb[(1023 - e) * Cn + c];
      }
      u_s[ll * 129 + c] = s * (1.0f / 64.0f);
    }
  }
  __syncthreads();

  // gate partials
  {
    const int o = og * 16 + (tid >> 4);
    const int cg = (tid & 15) * 8;
    float z = 0.f;
#pragma unroll
    for (int j = 0; j < 8; ++j) z += Wgate[o * Cn + cg + j] * ubar_s[cg + j];
    gpart[tid >> 4][tid & 15] = z;
  }

  // depthwise conv: thread = (lgrp 0..7 -> 8 l's, cq 0..31 -> 4 c's)
  const int lgrp = tid >> 5, l0 = lgrp * 8;
  const int cq = tid & 31, cdw = cq * 4;
  float4 wkv[KWn];
#pragma unroll
  for (int k = 0; k < KWn; ++k) {
    wkv[k].x = wdw_s[(cdw + 0) * KWn + k];
    wkv[k].y = wdw_s[(cdw + 1) * KWn + k];
    wkv[k].z = wdw_s[(cdw + 2) * KWn + k];
    wkv[k].w = wdw_s[(cdw + 3) * KWn + k];
  }
  const float4 z4 = make_float4(0.f, 0.f, 0.f, 0.f);
  float4 W9[9];
#pragma unroll
  for (int r = 0; r < 9; ++r) {
    const int ll = l0 - 4 + r;
    W9[r] = (ll >= 0 && ll < CYC) ? *(const float4*)&u_s[ll * 129 + cdw] : z4;
  }
  float4 hacc[8];
#pragma unroll
  for (int j = 0; j < 8; ++j) {
    float4 hv = z4;
#pragma unroll
    for (int k = 0; k < KWn; ++k) fma4(hv, W9[k], wkv[k]);
    hacc[j] = hv;
    if (j < 7) {
#pragma unroll
      for (int r = 0; r < 8; ++r) W9[r] = W9[r + 1];
      const int ll = l0 + j + 5;
      W9[8] = (ll < CYC) ? *(const float4*)&u_s[ll * 129 + cdw] : z4;
    }
  }
  __syncthreads();   // all u-view reads done

  // h1-view store [l][c] (b128), gates finalize
#pragma unroll
  for (int j = 0; j < 8; ++j) *(float4*)&u_s[(l0 + j) * 129 + cdw] = hacc[j];
  if (tid < 16) {
    float z = 0.f;
#pragma unroll
    for (int j = 0; j < 16; ++j) z += gpart[tid][j];
    gates_s[tid] = 1.0f / (1.0f + expf(-z));
  }
  __syncthreads();

  // pointwise: wave w -> 4 outputs; weights via wave-uniform global (s_load)
  const int o4 = og * 16 + w * 4;
  const float* wb = Wpw + (size_t)o4 * Cn;
  float acc[4] = {0.f, 0.f, 0.f, 0.f};
  for (int cb = 0; cb < Cn; cb += 4) {
    const float4 hv = *(const float4*)&u_s[l * 129 + cb];
#pragma unroll
    for (int i = 0; i < 4; ++i) {
      acc[i] = fmaf(wb[i * Cn + cb + 0], hv.x, acc[i]);
      acc[i] = fmaf(wb[i * Cn + cb + 1], hv.y, acc[i]);
      acc[i] = fmaf(wb[i * Cn + cb + 2], hv.z, acc[i]);
      acc[i] = fmaf(wb[i * Cn + cb + 3], hv.w, acc[i]);
    }
  }

  // GroupNorm: wave's 4 o == one GN group
  float s1 = acc[0] + acc[1] + acc[2] + acc[3];
  float s2 = acc[0]*acc[0] + acc[1]*acc[1] + acc[2]*acc[2] + acc[3]*acc[3];
#pragma unroll
  for (int m = 32; m > 0; m >>= 1) {
    s1 += __shfl_xor(s1, m, 64);
    s2 += __shfl_xor(s2, m, 64);
  }
  const float mean = s1 * (1.0f / 256.0f);
  const float var  = s2 * (1.0f / 256.0f) - mean * mean;
  const float rstd = rsqrtf(var + 1e-5f);

  float4 res;
  float* rp = (float*)&res;
#pragma unroll
  for (int i = 0; i < 4; ++i) {
    const int o = o4 + i;
    float h = (acc[i] - mean) * rstd;
    h = h * gnw[o] + gnb[o];
    h = 0.5f * h * (1.0f + erff(h * 0.70710678118654752440f));
    rp[i] = h * gates_s[w * 4 + i];
  }
  *(float4*)(hh + ((size_t)n * CYC + l) * Cn + o4) = res;
}

// ---------------------------------------------------------------------------
// K4: partial num/den per (b,q-chunk). grid (q=8, b=32), 512 thr. NO
// redundancy (R7's 8x-redundant dot caused 40MB fetch + 76us).
// ---------------------------------------------------------------------------
__global__ __launch_bounds__(512) void k_dot(const float* __restrict__ x,
    const float* __restrict__ hh, const float* __restrict__ pflt,
    const ushort4* __restrict__ cycs_g, const float* __restrict__ gamma,
    float* __restrict__ pna, float* __restrict__ pda) {
  const int q = blockIdx.x, b = blockIdx.y;
  const int tid = threadIdx.x;
  const int c = tid & 127, th = tid >> 7;   // th 0..3
  __shared__ ushort4 cyt[64];
  __shared__ float redn[4][Cn], redd[4][Cn];

  const float w0 = pflt[b * 4 + 0], w1 = pflt[b * 4 + 1], w2 = pflt[b * 4 + 2];
  const float sw = w0 + w1 + w2;
  if (tid < 64) cyt[tid] = cycs_g[(size_t)b * Tn + q * 64 + tid];
  __syncthreads();

  const float gam = gamma[c];
  const float* hh0 = hh + ((size_t)(b * 3 + 0) * CYC) * Cn + c;
  const float* hh1 = hh + ((size_t)(b * 3 + 1) * CYC) * Cn + c;
  const float* hh2 = hh + ((size_t)(b * 3 + 2) * CYC) * Cn + c;
  const float* xb = x + ((size_t)b * Tn + q * 64) * Cn;

  float na = 0.f, da = 0.f;
#pragma unroll 4
  for (int tt = th * 16; tt < th * 16 + 16; ++tt) {
    const ushort4 cy = cyt[tt];
    const float xv = xb[tt * Cn + c];
    const float dv = gam * (w0 * hh0[cy.x * Cn] + w1 * hh1[cy.y * Cn] + w2 * hh2[cy.z * Cn]);
    const float P = sw * xv + dv;
    na += (xv - P) * P;
    da += P * P;
  }
  redn[th][c] = na; redd[th][c] = da;
  __syncthreads();
  if (tid < Cn) {
    pna[((size_t)b * 8 + q) * Cn + tid] = redn[0][tid] + redn[1][tid] + redn[2][tid] + redn[3][tid];
    pda[((size_t)b * 8 + q) * Cn + tid] = redd[0][tid] + redd[1][tid] + redd[2][tid] + redd[3][tid];
  }
}

// ---------------------------------------------------------------------------
// K5: reduce partials (cheap), write out. grid (q=8, b=32), 512 thr.
// ---------------------------------------------------------------------------
__global__ __launch_bounds__(512) void k_out(const float* __restrict__ x,
    const float* __restrict__ hh, const float* __restrict__ pflt,
    const ushort4* __restrict__ cycs_g, const float* __restrict__ gamma,
    const float* __restrict__ pna, const float* __restrict__ pda,
    float* __restrict__ out) {
  const int q = blockIdx.x, b = blockIdx.y;
  const int tid = threadIdx.x;
  const int c = tid & 127, th = tid >> 7;
  __shared__ ushort4 cyt[64];

  const float w0 = pflt[b * 4 + 0], w1 = pflt[b * 4 + 1], w2 = pflt[b * 4 + 2];
  const float Gv = pflt[b * 4 + 3];
  const float sw = w0 + w1 + w2;
  if (tid < 64) cyt[tid] = cycs_g[(size_t)b * Tn + q * 64 + tid];
  __syncthreads();

  float num = 0.f, den = 1e-6f;
#pragma unroll
  for (int qq = 0; qq < 8; ++qq) {
    num += pna[((size_t)b * 8 + qq) * Cn + c];
    den += pda[((size_t)b * 8 + qq) * Cn + c];
  }
  const float sc = Gv * (num / den);

  const float gam = gamma[c];
  const float* hh0 = hh + ((size_t)(b * 3 + 0) * CYC) * Cn + c;
  const float* hh1 = hh + ((size_t)(b * 3 + 1) * CYC) * Cn + c;
  const float* hh2 = hh + ((size_t)(b * 3 + 2) * CYC) * Cn + c;
  const float* xb = x + ((size_t)b * Tn + q * 64) * Cn;
  float* ob = out + ((size_t)b * Tn + q * 64) * Cn;

#pragma unroll 4
  for (int tt = th * 16; tt < th * 16 + 16; ++tt) {
    const ushort4 cy = cyt[tt];
    const float xv = xb[tt * Cn + c];
    const float dv = gam * (w0 * hh0[cy.x * Cn] + w1 * hh1[cy.y * Cn] + w2 * hh2[cy.z * Cn]);
    const float P = sw * xv + dv;
    ob[tt * Cn + c] = xv - sc * P;
  }
}

// ---------------------------------------------------------------------------
extern "C" void kernel_launch(void* const* d_in, const int* in_sizes, int n_in,
                              void* d_out, int out_size, void* d_ws, size_t ws_size,
                              hipStream_t stream) {
  const float* x     = (const float*)d_in[0];
  const float* Wdw   = (const float*)d_in[1];
  const float* Wpw   = (const float*)d_in[2];
  const float* gnw   = (const float*)d_in[3];
  const float* gnb   = (const float*)d_in[4];
  const float* Wgate = (const float*)d_in[5];
  const float* gamma = (const float*)d_in[6];
  float* out = (float*)d_out;

  char* ws = (char*)d_ws;
  float*   r_ws   = (float*)ws;                     // 32*16*57 f (~117 KB)
  int*     pint   = (int*)(ws + 131072);
  float*   pflt   = (float*)(ws + 131584);
  ushort4* cycs_g = (ushort4*)(ws + 132096);        // 128 KB
  float*   pna    = (float*)(ws + 263168);          // 128 KB
  float*   pda    = (float*)(ws + 394240);          // 128 KB
  float*   Pp     = (float*)(ws + 525312);          // 8.4 MB
  float*   hh     = (float*)(ws + 525312 + 8404992);  // 3 MB

  k_front<<<512 + Bn, 256, 0, stream>>>(x, r_ws, Pp);
  k_params<<<Bn, 64, 0, stream>>>(r_ws, pint, pflt, cycs_g);
  k_foldconv<<<dim3(Bn * Kk, 8), 256, 0, stream>>>(Pp, pint, Wdw, Wpw, gnw, gnb, Wgate, hh);
  k_dot<<<dim3(8, Bn), 512, 0, stream>>>(x, hh, pflt, cycs_g, gamma, pna, pda);
  k_out<<<dim3(8, Bn), 512, 0, stream>>>(x, hh, pflt, cycs_g, gamma, pna, pda, out);
}